// Round 15
// baseline (191.412 us; speedup 1.0000x reference)
//
#include <hip/hip_runtime.h>
#include <hip/hip_bf16.h>
#include <stdint.h>

// dMoA forward: router(16 tok/block, LDS-wrt, 16 loads in flight) ->
// w1/w2 transpose+convert (8 tiles/block, 16 loads in flight, dbuf smem) ->
// dispatch(+prep) -> grouped map GEMM -> grouped reduce GEMM -> combine.
// T=8192, H=F=1024, E=8, top-k=2.
// GEMM core (R8): 128x128, BK=64, 4 waves, single-buffer 32KB LDS,
// XOR-swizzled, expert-pinned-to-XCD; at the structure-class shape ceiling.

#define HD 1024
#define FD 1024
#define EN 8

typedef __attribute__((ext_vector_type(8))) short bf16x8;
typedef __attribute__((ext_vector_type(4))) float f32x4;

__device__ __forceinline__ void gload16(const void* g, void* l) {
    __builtin_amdgcn_global_load_lds(
        (const __attribute__((address_space(1))) unsigned int*)g,
        (__attribute__((address_space(3))) unsigned int*)l, 16, 0, 0);
}

__device__ __forceinline__ ushort f2bf(float v) {
    __hip_bfloat16 h = __float2bfloat16(v);
    return *(ushort*)&h;
}
__device__ __forceinline__ float bf2f(ushort u) {
    unsigned int w = ((unsigned int)u) << 16;
    float f; __builtin_memcpy(&f, &w, 4); return f;
}

// ------------------------------------------------- router (+ x -> bf16 cast)
// 16 tokens/block; ALL 16 x-float4s issued before compute (256B/thread
// in flight); wrt staged once per block (contiguous 128B/thread reads).
__global__ __launch_bounds__(256) void router_kernel(
    const float* __restrict__ x, const float* __restrict__ wrt,
    ushort* __restrict__ xb,
    int* __restrict__ top_e, float* __restrict__ top_w,
    int* __restrict__ counts, float* __restrict__ probsum)
{
    __shared__ float lw[EN][HD];     // 32 KB, transposed: lw[e][h]
    __shared__ int   cnt_s[EN];
    __shared__ float ps_s[EN];
    int tid = threadIdx.x;
    int wid = tid >> 6, lane = tid & 63;

    // front-load all 16 x vectors (4 tokens x 4 chunks)
    float4 xv[4][4];
#pragma unroll
    for (int j = 0; j < 4; j++) {
        int t = blockIdx.x * 16 + wid * 4 + j;
        const float4* xr4 = (const float4*)(x + (size_t)t * HD);
#pragma unroll
        for (int it = 0; it < 4; it++) xv[j][it] = xr4[it * 64 + lane];
    }
    {   // stage wrt: thread tid covers h = 4*tid..4*tid+3 (contiguous 128B)
        const float4* w4p = (const float4*)(wrt + (size_t)tid * 32);
#pragma unroll
        for (int q = 0; q < 4; q++) {
            float4 a = w4p[q * 2], b = w4p[q * 2 + 1];
            int h = tid * 4 + q;
            lw[0][h] = a.x; lw[1][h] = a.y; lw[2][h] = a.z; lw[3][h] = a.w;
            lw[4][h] = b.x; lw[5][h] = b.y; lw[6][h] = b.z; lw[7][h] = b.w;
        }
    }
    if (tid < EN) { cnt_s[tid] = 0; ps_s[tid] = 0.f; }

    // xb stores (registers already in flight / arriving)
#pragma unroll
    for (int j = 0; j < 4; j++) {
        int t = blockIdx.x * 16 + wid * 4 + j;
        ushort4* xbo = (ushort4*)(xb + (size_t)t * HD);
#pragma unroll
        for (int it = 0; it < 4; it++) {
            ushort4 o; o.x = f2bf(xv[j][it].x); o.y = f2bf(xv[j][it].y);
            o.z = f2bf(xv[j][it].z); o.w = f2bf(xv[j][it].w);
            xbo[it * 64 + lane] = o;
        }
    }
    __syncthreads();                          // lw ready

#pragma unroll
    for (int j = 0; j < 4; j++) {
        int t = blockIdx.x * 16 + wid * 4 + j;
        float acc[EN];
#pragma unroll
        for (int e = 0; e < EN; e++) acc[e] = 0.f;
#pragma unroll
        for (int it = 0; it < 4; it++) {
            int h0 = it * 256 + lane * 4;
#pragma unroll
            for (int e = 0; e < EN; e++) {
                float4 w4 = *(const float4*)&lw[e][h0];
                acc[e] += xv[j][it].x * w4.x + xv[j][it].y * w4.y
                        + xv[j][it].z * w4.z + xv[j][it].w * w4.w;
            }
        }
#pragma unroll
        for (int off = 32; off >= 1; off >>= 1) {
#pragma unroll
            for (int e = 0; e < EN; e++) acc[e] += __shfl_xor(acc[e], off, 64);
        }
        if (lane == 0) {
            float m = acc[0];
#pragma unroll
            for (int e = 1; e < EN; e++) m = fmaxf(m, acc[e]);
            float p[EN], s = 0.f;
#pragma unroll
            for (int e = 0; e < EN; e++) { p[e] = expf(acc[e] - m); s += p[e]; }
            float inv = 1.f / s;
#pragma unroll
            for (int e = 0; e < EN; e++) p[e] *= inv;
            int e0 = 0;
#pragma unroll
            for (int e = 1; e < EN; e++) if (p[e] > p[e0]) e0 = e;  // strict >, first wins
            int e1 = (e0 == 0) ? 1 : 0;
#pragma unroll
            for (int e = 0; e < EN; e++) {
                if (e == e0) continue;
                if (p[e] > p[e1]) e1 = e;
            }
            top_e[t * 2] = e0;  top_e[t * 2 + 1] = e1;
            top_w[t * 2] = p[e0]; top_w[t * 2 + 1] = p[e1];
            atomicAdd(&cnt_s[e0], 1); atomicAdd(&cnt_s[e1], 1);
#pragma unroll
            for (int e = 0; e < EN; e++) atomicAdd(&ps_s[e], p[e]);
        }
    }
    __syncthreads();
    if (tid < EN) {
        atomicAdd(&counts[tid], cnt_s[tid]);
        atomicAdd(&probsum[tid], ps_s[tid]);
    }
}

// ---- w transpose + f32->bf16 convert: 8 tiles/block, 16 loads in flight
__global__ __launch_bounds__(256) void wconv_kernel(
    const float* __restrict__ w1, const float* __restrict__ w2,
    ushort* __restrict__ w1b, ushort* __restrict__ w2b)
{
    __shared__ float smem[2][32 * 68];         // 17.4 KB double-buffered
    int bid = blockIdx.x;
    int tid = threadIdx.x;
    const float* in; ushort* outp;
    if (bid >= 512) { in = w2; outp = w2b; bid -= 512; }
    else            { in = w1; outp = w1b; }
    int e    = bid >> 6;          // 64 blocks/expert
    int rm   = bid & 63;
    int kt   = rm >> 2;           // 16 kt (k0 = kt*64)
    int ntg2 = rm & 3;            // 4 groups of 8 nt-tiles (n0 = ntg2*256)
    const float* pin = in + ((size_t)e << 20) + (size_t)(kt * 64) * 1024 + ntg2 * 256;
    ushort* pout = outp + ((size_t)e << 20) + (size_t)(ntg2 * 256) * 1024 + kt * 64;

    int kk0 = tid >> 3, c4 = tid & 7;
    int kk1 = kk0 + 32;
    int n_r = tid >> 3, ks = (tid & 7) * 8;

    // front-load ALL 8 tiles' inputs: 16 independent 16B loads in flight
    float4 v[16];
#pragma unroll
    for (int t = 0; t < 8; t++) {
        v[2 * t]     = *(const float4*)(pin + (size_t)kk0 * 1024 + t * 32 + c4 * 4);
        v[2 * t + 1] = *(const float4*)(pin + (size_t)kk1 * 1024 + t * 32 + c4 * 4);
    }
#pragma unroll
    for (int t = 0; t < 8; t++) {
        float* buf = smem[t & 1];
        float* d0 = &buf[(c4 * 4) * 68 + kk0];
        float* d1 = &buf[(c4 * 4) * 68 + kk1];
        d0[0] = v[2 * t].x; d0[68] = v[2 * t].y; d0[136] = v[2 * t].z; d0[204] = v[2 * t].w;
        d1[0] = v[2 * t + 1].x; d1[68] = v[2 * t + 1].y; d1[136] = v[2 * t + 1].z; d1[204] = v[2 * t + 1].w;
        __syncthreads();                       // write(t)->read(t); read(t-2) done
        float4 f0 = *(const float4*)&buf[n_r * 68 + ks];
        float4 f1 = *(const float4*)&buf[n_r * 68 + ks + 4];
        ushort us[8];
        us[0] = f2bf(f0.x); us[1] = f2bf(f0.y); us[2] = f2bf(f0.z); us[3] = f2bf(f0.w);
        us[4] = f2bf(f1.x); us[5] = f2bf(f1.y); us[6] = f2bf(f1.z); us[7] = f2bf(f1.w);
        *(uint4*)(pout + (size_t)(t * 32 + n_r) * 1024 + ks) = *(uint4*)us;
    }
}

// ------------------------------------------- dispatch (+ inlined prep/loss)
__global__ __launch_bounds__(256) void dispatch_kernel(
    const int* __restrict__ counts, const float* __restrict__ probsum,
    const int* __restrict__ top_e, const float* __restrict__ top_w,
    int* __restrict__ cursor, int* __restrict__ tok_list,
    float* __restrict__ w_list, int* __restrict__ offs_g,
    float* __restrict__ loss_out)
{
    int offs[EN + 1]; offs[0] = 0;
#pragma unroll
    for (int e = 0; e < EN; e++) offs[e + 1] = offs[e] + counts[e];
    if (blockIdx.x == 0 && threadIdx.x == 0) {
        float loss = 0.f;
#pragma unroll
        for (int e = 0; e < EN; e++) {
            offs_g[e] = offs[e];
            loss += ((float)counts[e] / 16384.f) * (probsum[e] / 8192.f);
        }
        offs_g[EN] = offs[EN];
        *loss_out = 8.f * loss;
    }
    int t = blockIdx.x * 256 + threadIdx.x;   // grid 32*256 == 8192 exactly
    int lane = threadIdx.x & 63;
#pragma unroll
    for (int k = 0; k < 2; k++) {
        int e = top_e[t * 2 + k];
        int idx = 0;
#pragma unroll
        for (int ex = 0; ex < EN; ex++) {
            unsigned long long m = __ballot(e == ex);
            if (e == ex) {
                int cnt = __popcll(m);
                int leader = __ffsll(m) - 1;
                int pos = 0;
                if (lane == leader) pos = atomicAdd(&cursor[ex * 16], cnt);
                pos = __shfl(pos, leader, 64);
                int rank = __popcll(m & ((1ull << lane) - 1ull));
                idx = offs[ex] + pos + rank;
            }
        }
        tok_list[idx] = t * 2 + k;            // encode (token, k)
        w_list[idx] = top_w[t * 2 + k];
    }
}

// =================== grouped GEMM core (m97 structure, R8 verbatim) =========
__global__ __launch_bounds__(256) void map_gemm(
    const ushort* __restrict__ xb, const ushort* __restrict__ w1b,
    ushort* __restrict__ hbuf,
    const int* __restrict__ tok_list, const float* __restrict__ w_list,
    const int* __restrict__ offs)
{
    __shared__ __align__(16) short lA[128][64];   // 16 KB
    __shared__ __align__(16) short lB[128][64];   // 16 KB
    __shared__ int   tok_s[128];
    __shared__ float wt_s[128];

    int g = blockIdx.x;
    int e = g & 7, q = g >> 3, nb = q & 7, rb = q >> 3;
    int base = offs[e], cnt = offs[e + 1] - base;
    int row0 = rb << 7;
    if (row0 >= cnt) return;
    int rem = cnt - row0;
    int tid = threadIdx.x;
    if (tid < 128) {
        int r = row0 + tid; if (r > cnt - 1) r = cnt - 1;   // clamp
        tok_s[tid] = tok_list[base + r];
        wt_s[tid]  = w_list[base + r];
    }
    __syncthreads();

    int lane = tid & 63, w = tid >> 6;
    int wm = w >> 1, wn = w & 1;
    int lo = lane & 15, hi = lane >> 4, rx = lane & 7;

    int lr = lane >> 3;
    int kseg = ((lane & 7) ^ lr) << 3;
    const ushort* pA[4]; const ushort* pB[4];
    const ushort* wbase = w1b + ((size_t)e << 20);
#pragma unroll
    for (int i = 0; i < 4; i++) {
        int rowT = w * 32 + i * 8 + lr;
        pA[i] = xb + (size_t)(tok_s[rowT] >> 1) * HD + kseg;
        pB[i] = wbase + (size_t)(nb * 128 + rowT) * HD + kseg;
    }

    f32x4 acc[4][4];
#pragma unroll
    for (int m = 0; m < 4; m++)
#pragma unroll
        for (int n = 0; n < 4; n++) acc[m][n] = (f32x4){0.f, 0.f, 0.f, 0.f};

    for (int kt = 0; kt < 16; ++kt) {
#pragma unroll
        for (int i = 0; i < 4; i++) {
            int rowT = w * 32 + i * 8 + lr;
            gload16(pA[i], &lA[rowT][0]);
            gload16(pB[i], &lB[rowT][0]);
            pA[i] += 64; pB[i] += 64;
        }
        __syncthreads();
        bf16x8 af[4][2], bg[4][2];
#pragma unroll
        for (int m = 0; m < 4; m++)
#pragma unroll
            for (int ks = 0; ks < 2; ks++)
                af[m][ks] = *(const bf16x8*)&lA[wm * 64 + m * 16 + lo][((ks * 4 + hi) ^ rx) << 3];
#pragma unroll
        for (int n = 0; n < 4; n++)
#pragma unroll
            for (int ks = 0; ks < 2; ks++)
                bg[n][ks] = *(const bf16x8*)&lB[wn * 64 + n * 16 + lo][((ks * 4 + hi) ^ rx) << 3];
#pragma unroll
        for (int ks = 0; ks < 2; ks++)
#pragma unroll
            for (int m = 0; m < 4; m++)
#pragma unroll
                for (int n = 0; n < 4; n++)
                    acc[m][n] = __builtin_amdgcn_mfma_f32_16x16x32_bf16(af[m][ks], bg[n][ks], acc[m][n], 0, 0, 0);
        __syncthreads();
    }

    short* ep = ((short*)lA) + w * 4096;
#pragma unroll
    for (int m = 0; m < 4; m++)
#pragma unroll
        for (int r = 0; r < 4; r++) {
            int row_l = m * 16 + hi * 4 + r;
            int rswz = (row_l & 7) << 4;
            float wgt = wt_s[wm * 64 + row_l];
#pragma unroll
            for (int n = 0; n < 4; n++) {
                int colb = (n * 16 + lo) * 2;
                ep[(row_l * 128 + (colb ^ rswz)) >> 1] = f2bf(acc[m][n][r] * wgt);
            }
        }
    __syncthreads();
    size_t outbase = (size_t)(base + row0);
    int colg0 = (nb << 7) + wn * 64;
#pragma unroll
    for (int j = 0; j < 8; j++) {
        int row_l = j * 8 + (lane >> 3);
        int r_blk = wm * 64 + row_l;
        int sb = ((lane & 7) * 16) ^ ((row_l & 7) << 4);
        bf16x8 v = *(const bf16x8*)&ep[(row_l * 128 + sb) >> 1];
        if (r_blk < rem)
            *(bf16x8*)&hbuf[(outbase + r_blk) * FD + colg0 + (lane & 7) * 8] = v;
    }
}

__global__ __launch_bounds__(256) void reduce_gemm(
    const ushort* __restrict__ hbuf, const ushort* __restrict__ w2b,
    ushort* __restrict__ obuf,
    const int* __restrict__ tok_list, const int* __restrict__ offs)
{
    __shared__ __align__(16) short lA[128][64];
    __shared__ __align__(16) short lB[128][64];
    __shared__ int tok_s[128];

    int g = blockIdx.x;
    int e = g & 7, q = g >> 3, nb = q & 7, rb = q >> 3;
    int base = offs[e], cnt = offs[e + 1] - base;
    int row0 = rb << 7;
    if (row0 >= cnt) return;
    int rem = cnt - row0;
    int tid = threadIdx.x;
    if (tid < 128) {
        int r = row0 + tid; if (r > cnt - 1) r = cnt - 1;
        tok_s[tid] = tok_list[base + r];
    }
    __syncthreads();

    int lane = tid & 63, w = tid >> 6;
    int wm = w >> 1, wn = w & 1;
    int lo = lane & 15, hi = lane >> 4, rx = lane & 7;

    int lr = lane >> 3;
    int kseg = ((lane & 7) ^ lr) << 3;
    const ushort* pA[4]; const ushort* pB[4];
    const ushort* wbase = w2b + ((size_t)e << 20);
#pragma unroll
    for (int i = 0; i < 4; i++) {
        int rowT = w * 32 + i * 8 + lr;
        int ar = row0 + rowT; if (ar > cnt - 1) ar = cnt - 1;
        pA[i] = hbuf + (size_t)(base + ar) * FD + kseg;
        pB[i] = wbase + (size_t)(nb * 128 + rowT) * FD + kseg;
    }

    f32x4 acc[4][4];
#pragma unroll
    for (int m = 0; m < 4; m++)
#pragma unroll
        for (int n = 0; n < 4; n++) acc[m][n] = (f32x4){0.f, 0.f, 0.f, 0.f};

    for (int kt = 0; kt < 16; ++kt) {
#pragma unroll
        for (int i = 0; i < 4; i++) {
            int rowT = w * 32 + i * 8 + lr;
            gload16(pA[i], &lA[rowT][0]);
            gload16(pB[i], &lB[rowT][0]);
            pA[i] += 64; pB[i] += 64;
        }
        __syncthreads();
        bf16x8 af[4][2], bg[4][2];
#pragma unroll
        for (int m = 0; m < 4; m++)
#pragma unroll
            for (int ks = 0; ks < 2; ks++)
                af[m][ks] = *(const bf16x8*)&lA[wm * 64 + m * 16 + lo][((ks * 4 + hi) ^ rx) << 3];
#pragma unroll
        for (int n = 0; n < 4; n++)
#pragma unroll
            for (int ks = 0; ks < 2; ks++)
                bg[n][ks] = *(const bf16x8*)&lB[wn * 64 + n * 16 + lo][((ks * 4 + hi) ^ rx) << 3];
#pragma unroll
        for (int ks = 0; ks < 2; ks++)
#pragma unroll
            for (int m = 0; m < 4; m++)
#pragma unroll
                for (int n = 0; n < 4; n++)
                    acc[m][n] = __builtin_amdgcn_mfma_f32_16x16x32_bf16(af[m][ks], bg[n][ks], acc[m][n], 0, 0, 0);
        __syncthreads();
    }

    short* ep = ((short*)lA) + w * 4096;
#pragma unroll
    for (int m = 0; m < 4; m++)
#pragma unroll
        for (int r = 0; r < 4; r++) {
            int row_l = m * 16 + hi * 4 + r;
            int rswz = (row_l & 7) << 4;
#pragma unroll
            for (int n = 0; n < 4; n++) {
                int colb = (n * 16 + lo) * 2;
                ep[(row_l * 128 + (colb ^ rswz)) >> 1] = f2bf(acc[m][n][r]);
            }
        }
    __syncthreads();
    int colg0 = (nb << 7) + wn * 64;
#pragma unroll
    for (int j = 0; j < 8; j++) {
        int row_l = j * 8 + (lane >> 3);
        int r_blk = wm * 64 + row_l;
        int sb = ((lane & 7) * 16) ^ ((row_l & 7) << 4);
        bf16x8 v = *(const bf16x8*)&ep[(row_l * 128 + sb) >> 1];
        if (r_blk < rem)
            *(bf16x8*)&obuf[(size_t)tok_s[r_blk] * HD + colg0 + (lane & 7) * 8] = v;
    }
}

// ------------------------------------------------------------------ combine
__global__ __launch_bounds__(256) void combine_kernel(
    const ushort* __restrict__ obuf, float* __restrict__ out)
{
    int g = blockIdx.x * 256 + threadIdx.x;      // grid 4096 -> 1M threads
    int t = g >> 7, c8 = (g & 127) << 3;
    const ushort* p = obuf + (size_t)t * 2048 + c8;
    bf16x8 a = *(const bf16x8*)p;
    bf16x8 b = *(const bf16x8*)(p + 1024);
    float o[8];
#pragma unroll
    for (int i = 0; i < 8; i++)
        o[i] = bf2f((ushort)a[i]) + bf2f((ushort)b[i]);
    float* q = out + (size_t)t * HD + c8;
    *(float4*)q       = (float4){o[0], o[1], o[2], o[3]};
    *(float4*)(q + 4) = (float4){o[4], o[5], o[6], o[7]};
}

// ---------------------------------------------------------------- launcher
extern "C" void kernel_launch(void* const* d_in, const int* in_sizes, int n_in,
                              void* d_out, int out_size, void* d_ws, size_t ws_size,
                              hipStream_t stream)
{
    const float* x   = (const float*)d_in[0];
    const float* wrt = (const float*)d_in[1];
    const float* w1  = (const float*)d_in[2];
    const float* w2  = (const float*)d_in[3];
    float* out = (float*)d_out;

    // workspace carve (~80.3 MB); obuf aliases xb+w1b (dead after map_gemm)
    uint8_t* ws = (uint8_t*)d_ws;
    ushort* xb   = (ushort*)(ws);                    // 16 MB  [T][H] bf16
    ushort* w1b  = (ushort*)(ws + (16u << 20));      // 16 MB  [E][F][H] bf16
    ushort* obuf = (ushort*)(ws);                    // 32 MB  [2T][H] bf16 (alias)
    ushort* w2b  = (ushort*)(ws + (32u << 20));      // 16 MB  [E][H][F] bf16
    ushort* hbuf = (ushort*)(ws + (48u << 20));      // 32 MB  [2T][F] bf16
    uint8_t* p80 = ws + (80u << 20);
    int*   tok_list = (int*)(p80);                   // 64 KB
    float* w_list   = (float*)(p80 + (64u << 10));   // 64 KB
    int*   top_e    = (int*)(p80 + (128u << 10));    // 64 KB
    float* top_w    = (float*)(p80 + (192u << 10));  // 64 KB
    uint8_t* ctr    = p80 + (256u << 10);
    int*   counts   = (int*)(ctr);                   // 8 ints
    float* probsum  = (float*)(ctr + 64);            // 8 floats
    int*   offs     = (int*)(ctr + 128);             // 9 ints
    int*   cursor   = (int*)(ctr + 256);             // 8 * 16 ints (padded lines)
    float* loss_out = out + 8388608;

    hipMemsetAsync(ctr, 0, 1024, stream);

    router_kernel<<<512, 256, 0, stream>>>(x, wrt, xb, top_e, top_w, counts, probsum);
    wconv_kernel<<<1024, 256, 0, stream>>>(w1, w2, w1b, w2b);
    dispatch_kernel<<<32, 256, 0, stream>>>(counts, probsum, top_e, top_w,
                                            cursor, tok_list, w_list, offs, loss_out);
    // grid: rb(18) x nb(8) x e(8); e = low 3 bits -> XCD pin
    map_gemm<<<1152, 256, 0, stream>>>(xb, w1b, hbuf, tok_list, w_list, offs);
    reduce_gemm<<<1152, 256, 0, stream>>>(hbuf, w2b, obuf, tok_list, offs);
    combine_kernel<<<4096, 256, 0, stream>>>(obuf, out);
}

// Round 16
// 184.803 us; speedup vs baseline: 1.0358x; 1.0358x over previous
//
#include <hip/hip_runtime.h>
#include <hip/hip_bf16.h>
#include <stdint.h>

// dMoA forward: router(16 tok/block, LDS-wrt) -> w1/w2 transpose+convert
// (dbuf smem) -> dispatch(+prep) -> grouped map GEMM -> grouped reduce GEMM
// -> combine.  T=8192, H=F=1024, E=8, top-k=2.
// GEMM core (R8): 128x128, BK=64, 4 waves, single-buffer 32KB LDS,
// XOR-swizzled, expert-pinned-to-XCD. At the m102 shape-curve ceiling for
// this per-expert shape (M~2048,N=K=1024).  [R14 configuration — best measured]

#define HD 1024
#define FD 1024
#define EN 8

typedef __attribute__((ext_vector_type(8))) short bf16x8;
typedef __attribute__((ext_vector_type(4))) float f32x4;

__device__ __forceinline__ void gload16(const void* g, void* l) {
    __builtin_amdgcn_global_load_lds(
        (const __attribute__((address_space(1))) unsigned int*)g,
        (__attribute__((address_space(3))) unsigned int*)l, 16, 0, 0);
}

__device__ __forceinline__ ushort f2bf(float v) {
    __hip_bfloat16 h = __float2bfloat16(v);
    return *(ushort*)&h;
}
__device__ __forceinline__ float bf2f(ushort u) {
    unsigned int w = ((unsigned int)u) << 16;
    float f; __builtin_memcpy(&f, &w, 4); return f;
}

// ------------------------------------------------- router (+ x -> bf16 cast)
// 16 tokens/block (4/wave): wrt L2 traffic 64->16 MB; staging loads are 32
// contiguous floats/thread. Compute reads lw[e][h0] as float4.
__global__ __launch_bounds__(256) void router_kernel(
    const float* __restrict__ x, const float* __restrict__ wrt,
    ushort* __restrict__ xb,
    int* __restrict__ top_e, float* __restrict__ top_w,
    int* __restrict__ counts, float* __restrict__ probsum)
{
    __shared__ float lw[EN][HD];     // 32 KB, transposed: lw[e][h]
    __shared__ int   cnt_s[EN];
    __shared__ float ps_s[EN];
    int tid = threadIdx.x;
    {   // stage wrt: thread tid covers h = 4*tid..4*tid+3 (contiguous 128B read)
        const float4* w4p = (const float4*)(wrt + (size_t)tid * 32);
#pragma unroll
        for (int q = 0; q < 4; q++) {
            float4 a = w4p[q * 2], b = w4p[q * 2 + 1];
            int h = tid * 4 + q;
            lw[0][h] = a.x; lw[1][h] = a.y; lw[2][h] = a.z; lw[3][h] = a.w;
            lw[4][h] = b.x; lw[5][h] = b.y; lw[6][h] = b.z; lw[7][h] = b.w;
        }
    }
    if (tid < EN) { cnt_s[tid] = 0; ps_s[tid] = 0.f; }
    __syncthreads();

    int wid = tid >> 6, lane = tid & 63;
#pragma unroll
    for (int j = 0; j < 4; j++) {
        int t = blockIdx.x * 16 + wid * 4 + j;   // 512 blocks * 16 = 8192
        const float4* xr4 = (const float4*)(x + (size_t)t * HD);
        ushort4* xbo = (ushort4*)(xb + (size_t)t * HD);
        float4 xv[4];
#pragma unroll
        for (int it = 0; it < 4; it++) xv[it] = xr4[it * 64 + lane];
#pragma unroll
        for (int it = 0; it < 4; it++) {
            ushort4 o; o.x = f2bf(xv[it].x); o.y = f2bf(xv[it].y);
            o.z = f2bf(xv[it].z); o.w = f2bf(xv[it].w);
            xbo[it * 64 + lane] = o;
        }
        float acc[EN];
#pragma unroll
        for (int e = 0; e < EN; e++) acc[e] = 0.f;
#pragma unroll
        for (int it = 0; it < 4; it++) {
            int h0 = it * 256 + lane * 4;
#pragma unroll
            for (int e = 0; e < EN; e++) {
                float4 w4 = *(const float4*)&lw[e][h0];
                acc[e] += xv[it].x * w4.x + xv[it].y * w4.y
                        + xv[it].z * w4.z + xv[it].w * w4.w;
            }
        }
#pragma unroll
        for (int off = 32; off >= 1; off >>= 1) {
#pragma unroll
            for (int e = 0; e < EN; e++) acc[e] += __shfl_xor(acc[e], off, 64);
        }
        if (lane == 0) {
            float m = acc[0];
#pragma unroll
            for (int e = 1; e < EN; e++) m = fmaxf(m, acc[e]);
            float p[EN], s = 0.f;
#pragma unroll
            for (int e = 0; e < EN; e++) { p[e] = expf(acc[e] - m); s += p[e]; }
            float inv = 1.f / s;
#pragma unroll
            for (int e = 0; e < EN; e++) p[e] *= inv;
            int e0 = 0;
#pragma unroll
            for (int e = 1; e < EN; e++) if (p[e] > p[e0]) e0 = e;  // strict >, first wins
            int e1 = (e0 == 0) ? 1 : 0;
#pragma unroll
            for (int e = 0; e < EN; e++) {
                if (e == e0) continue;
                if (p[e] > p[e1]) e1 = e;
            }
            top_e[t * 2] = e0;  top_e[t * 2 + 1] = e1;
            top_w[t * 2] = p[e0]; top_w[t * 2 + 1] = p[e1];
            atomicAdd(&cnt_s[e0], 1); atomicAdd(&cnt_s[e1], 1);
#pragma unroll
            for (int e = 0; e < EN; e++) atomicAdd(&ps_s[e], p[e]);
        }
    }
    __syncthreads();
    if (tid < EN) {
        atomicAdd(&counts[tid], cnt_s[tid]);
        atomicAdd(&probsum[tid], ps_s[tid]);
    }
}

// ---------------- w transpose + f32->bf16 convert (dbuf smem, 4 barriers)
__global__ __launch_bounds__(256) void wconv_kernel(
    const float* __restrict__ w1, const float* __restrict__ w2,
    ushort* __restrict__ w1b, ushort* __restrict__ w2b)
{
    __shared__ float smem[2][32 * 68];         // 17.4 KB double-buffered
    int bid = blockIdx.x;
    int tid = threadIdx.x;
    const float* in; ushort* outp;
    if (bid >= 1024) { in = w2; outp = w2b; bid -= 1024; }
    else             { in = w1; outp = w1b; }
    int e   = bid >> 7;
    int rm  = bid & 127;
    int kt  = rm >> 3;
    int ntg = rm & 7;
    const float* pin = in + ((size_t)e << 20) + (size_t)(kt * 64) * 1024 + ntg * 128;
    ushort* pout = outp + ((size_t)e << 20) + (size_t)(ntg * 128) * 1024 + kt * 64;

    int kk0 = tid >> 3, c4 = tid & 7;
    int kk1 = kk0 + 32;
    int n_r = tid >> 3, ks = (tid & 7) * 8;

    float4 v[8];
#pragma unroll
    for (int t = 0; t < 4; t++) {
        v[2 * t]     = *(const float4*)(pin + (size_t)kk0 * 1024 + t * 32 + c4 * 4);
        v[2 * t + 1] = *(const float4*)(pin + (size_t)kk1 * 1024 + t * 32 + c4 * 4);
    }
#pragma unroll
    for (int t = 0; t < 4; t++) {
        float* buf = smem[t & 1];
        float* d0 = &buf[(c4 * 4) * 68 + kk0];
        float* d1 = &buf[(c4 * 4) * 68 + kk1];
        d0[0] = v[2 * t].x; d0[68] = v[2 * t].y; d0[136] = v[2 * t].z; d0[204] = v[2 * t].w;
        d1[0] = v[2 * t + 1].x; d1[68] = v[2 * t + 1].y; d1[136] = v[2 * t + 1].z; d1[204] = v[2 * t + 1].w;
        __syncthreads();                       // write(t) -> read(t); also
                                               // guarantees read(t-2) done
        float4 f0 = *(const float4*)&buf[n_r * 68 + ks];
        float4 f1 = *(const float4*)&buf[n_r * 68 + ks + 4];
        ushort us[8];
        us[0] = f2bf(f0.x); us[1] = f2bf(f0.y); us[2] = f2bf(f0.z); us[3] = f2bf(f0.w);
        us[4] = f2bf(f1.x); us[5] = f2bf(f1.y); us[6] = f2bf(f1.z); us[7] = f2bf(f1.w);
        *(uint4*)(pout + (size_t)(t * 32 + n_r) * 1024 + ks) = *(uint4*)us;
    }
}

// ------------------------------------------- dispatch (+ inlined prep/loss)
__global__ __launch_bounds__(256) void dispatch_kernel(
    const int* __restrict__ counts, const float* __restrict__ probsum,
    const int* __restrict__ top_e, const float* __restrict__ top_w,
    int* __restrict__ cursor, int* __restrict__ tok_list,
    float* __restrict__ w_list, int* __restrict__ offs_g,
    float* __restrict__ loss_out)
{
    int offs[EN + 1]; offs[0] = 0;
#pragma unroll
    for (int e = 0; e < EN; e++) offs[e + 1] = offs[e] + counts[e];
    if (blockIdx.x == 0 && threadIdx.x == 0) {
        float loss = 0.f;
#pragma unroll
        for (int e = 0; e < EN; e++) {
            offs_g[e] = offs[e];
            loss += ((float)counts[e] / 16384.f) * (probsum[e] / 8192.f);
        }
        offs_g[EN] = offs[EN];
        *loss_out = 8.f * loss;
    }
    int t = blockIdx.x * 256 + threadIdx.x;   // grid 32*256 == 8192 exactly
    int lane = threadIdx.x & 63;
#pragma unroll
    for (int k = 0; k < 2; k++) {
        int e = top_e[t * 2 + k];
        int idx = 0;
#pragma unroll
        for (int ex = 0; ex < EN; ex++) {
            unsigned long long m = __ballot(e == ex);
            if (e == ex) {
                int cnt = __popcll(m);
                int leader = __ffsll(m) - 1;
                int pos = 0;
                if (lane == leader) pos = atomicAdd(&cursor[ex * 16], cnt);
                pos = __shfl(pos, leader, 64);
                int rank = __popcll(m & ((1ull << lane) - 1ull));
                idx = offs[ex] + pos + rank;
            }
        }
        tok_list[idx] = t * 2 + k;            // encode (token, k)
        w_list[idx] = top_w[t * 2 + k];
    }
}

// =================== grouped GEMM core (m97 structure, R8 verbatim) =========
__global__ __launch_bounds__(256) void map_gemm(
    const ushort* __restrict__ xb, const ushort* __restrict__ w1b,
    ushort* __restrict__ hbuf,
    const int* __restrict__ tok_list, const float* __restrict__ w_list,
    const int* __restrict__ offs)
{
    __shared__ __align__(16) short lA[128][64];   // 16 KB
    __shared__ __align__(16) short lB[128][64];   // 16 KB
    __shared__ int   tok_s[128];
    __shared__ float wt_s[128];

    int g = blockIdx.x;
    int e = g & 7, q = g >> 3, nb = q & 7, rb = q >> 3;
    int base = offs[e], cnt = offs[e + 1] - base;
    int row0 = rb << 7;
    if (row0 >= cnt) return;
    int rem = cnt - row0;
    int tid = threadIdx.x;
    if (tid < 128) {
        int r = row0 + tid; if (r > cnt - 1) r = cnt - 1;   // clamp
        tok_s[tid] = tok_list[base + r];
        wt_s[tid]  = w_list[base + r];
    }
    __syncthreads();

    int lane = tid & 63, w = tid >> 6;
    int wm = w >> 1, wn = w & 1;
    int lo = lane & 15, hi = lane >> 4, rx = lane & 7;

    int lr = lane >> 3;
    int kseg = ((lane & 7) ^ lr) << 3;
    const ushort* pA[4]; const ushort* pB[4];
    const ushort* wbase = w1b + ((size_t)e << 20);
#pragma unroll
    for (int i = 0; i < 4; i++) {
        int rowT = w * 32 + i * 8 + lr;
        pA[i] = xb + (size_t)(tok_s[rowT] >> 1) * HD + kseg;
        pB[i] = wbase + (size_t)(nb * 128 + rowT) * HD + kseg;
    }

    f32x4 acc[4][4];
#pragma unroll
    for (int m = 0; m < 4; m++)
#pragma unroll
        for (int n = 0; n < 4; n++) acc[m][n] = (f32x4){0.f, 0.f, 0.f, 0.f};

    for (int kt = 0; kt < 16; ++kt) {
#pragma unroll
        for (int i = 0; i < 4; i++) {
            int rowT = w * 32 + i * 8 + lr;
            gload16(pA[i], &lA[rowT][0]);
            gload16(pB[i], &lB[rowT][0]);
            pA[i] += 64; pB[i] += 64;
        }
        __syncthreads();
        bf16x8 af[4][2], bg[4][2];
#pragma unroll
        for (int m = 0; m < 4; m++)
#pragma unroll
            for (int ks = 0; ks < 2; ks++)
                af[m][ks] = *(const bf16x8*)&lA[wm * 64 + m * 16 + lo][((ks * 4 + hi) ^ rx) << 3];
#pragma unroll
        for (int n = 0; n < 4; n++)
#pragma unroll
            for (int ks = 0; ks < 2; ks++)
                bg[n][ks] = *(const bf16x8*)&lB[wn * 64 + n * 16 + lo][((ks * 4 + hi) ^ rx) << 3];
#pragma unroll
        for (int ks = 0; ks < 2; ks++)
#pragma unroll
            for (int m = 0; m < 4; m++)
#pragma unroll
                for (int n = 0; n < 4; n++)
                    acc[m][n] = __builtin_amdgcn_mfma_f32_16x16x32_bf16(af[m][ks], bg[n][ks], acc[m][n], 0, 0, 0);
        __syncthreads();
    }

    short* ep = ((short*)lA) + w * 4096;
#pragma unroll
    for (int m = 0; m < 4; m++)
#pragma unroll
        for (int r = 0; r < 4; r++) {
            int row_l = m * 16 + hi * 4 + r;
            int rswz = (row_l & 7) << 4;
            float wgt = wt_s[wm * 64 + row_l];
#pragma unroll
            for (int n = 0; n < 4; n++) {
                int colb = (n * 16 + lo) * 2;
                ep[(row_l * 128 + (colb ^ rswz)) >> 1] = f2bf(acc[m][n][r] * wgt);
            }
        }
    __syncthreads();
    size_t outbase = (size_t)(base + row0);
    int colg0 = (nb << 7) + wn * 64;
#pragma unroll
    for (int j = 0; j < 8; j++) {
        int row_l = j * 8 + (lane >> 3);
        int r_blk = wm * 64 + row_l;
        int sb = ((lane & 7) * 16) ^ ((row_l & 7) << 4);
        bf16x8 v = *(const bf16x8*)&ep[(row_l * 128 + sb) >> 1];
        if (r_blk < rem)
            *(bf16x8*)&hbuf[(outbase + r_blk) * FD + colg0 + (lane & 7) * 8] = v;
    }
}

__global__ __launch_bounds__(256) void reduce_gemm(
    const ushort* __restrict__ hbuf, const ushort* __restrict__ w2b,
    ushort* __restrict__ obuf,
    const int* __restrict__ tok_list, const int* __restrict__ offs)
{
    __shared__ __align__(16) short lA[128][64];
    __shared__ __align__(16) short lB[128][64];
    __shared__ int tok_s[128];

    int g = blockIdx.x;
    int e = g & 7, q = g >> 3, nb = q & 7, rb = q >> 3;
    int base = offs[e], cnt = offs[e + 1] - base;
    int row0 = rb << 7;
    if (row0 >= cnt) return;
    int rem = cnt - row0;
    int tid = threadIdx.x;
    if (tid < 128) {
        int r = row0 + tid; if (r > cnt - 1) r = cnt - 1;
        tok_s[tid] = tok_list[base + r];
    }
    __syncthreads();

    int lane = tid & 63, w = tid >> 6;
    int wm = w >> 1, wn = w & 1;
    int lo = lane & 15, hi = lane >> 4, rx = lane & 7;

    int lr = lane >> 3;
    int kseg = ((lane & 7) ^ lr) << 3;
    const ushort* pA[4]; const ushort* pB[4];
    const ushort* wbase = w2b + ((size_t)e << 20);
#pragma unroll
    for (int i = 0; i < 4; i++) {
        int rowT = w * 32 + i * 8 + lr;
        int ar = row0 + rowT; if (ar > cnt - 1) ar = cnt - 1;
        pA[i] = hbuf + (size_t)(base + ar) * FD + kseg;
        pB[i] = wbase + (size_t)(nb * 128 + rowT) * FD + kseg;
    }

    f32x4 acc[4][4];
#pragma unroll
    for (int m = 0; m < 4; m++)
#pragma unroll
        for (int n = 0; n < 4; n++) acc[m][n] = (f32x4){0.f, 0.f, 0.f, 0.f};

    for (int kt = 0; kt < 16; ++kt) {
#pragma unroll
        for (int i = 0; i < 4; i++) {
            int rowT = w * 32 + i * 8 + lr;
            gload16(pA[i], &lA[rowT][0]);
            gload16(pB[i], &lB[rowT][0]);
            pA[i] += 64; pB[i] += 64;
        }
        __syncthreads();
        bf16x8 af[4][2], bg[4][2];
#pragma unroll
        for (int m = 0; m < 4; m++)
#pragma unroll
            for (int ks = 0; ks < 2; ks++)
                af[m][ks] = *(const bf16x8*)&lA[wm * 64 + m * 16 + lo][((ks * 4 + hi) ^ rx) << 3];
#pragma unroll
        for (int n = 0; n < 4; n++)
#pragma unroll
            for (int ks = 0; ks < 2; ks++)
                bg[n][ks] = *(const bf16x8*)&lB[wn * 64 + n * 16 + lo][((ks * 4 + hi) ^ rx) << 3];
#pragma unroll
        for (int ks = 0; ks < 2; ks++)
#pragma unroll
            for (int m = 0; m < 4; m++)
#pragma unroll
                for (int n = 0; n < 4; n++)
                    acc[m][n] = __builtin_amdgcn_mfma_f32_16x16x32_bf16(af[m][ks], bg[n][ks], acc[m][n], 0, 0, 0);
        __syncthreads();
    }

    short* ep = ((short*)lA) + w * 4096;
#pragma unroll
    for (int m = 0; m < 4; m++)
#pragma unroll
        for (int r = 0; r < 4; r++) {
            int row_l = m * 16 + hi * 4 + r;
            int rswz = (row_l & 7) << 4;
#pragma unroll
            for (int n = 0; n < 4; n++) {
                int colb = (n * 16 + lo) * 2;
                ep[(row_l * 128 + (colb ^ rswz)) >> 1] = f2bf(acc[m][n][r]);
            }
        }
    __syncthreads();
    int colg0 = (nb << 7) + wn * 64;
#pragma unroll
    for (int j = 0; j < 8; j++) {
        int row_l = j * 8 + (lane >> 3);
        int r_blk = wm * 64 + row_l;
        int sb = ((lane & 7) * 16) ^ ((row_l & 7) << 4);
        bf16x8 v = *(const bf16x8*)&ep[(row_l * 128 + sb) >> 1];
        if (r_blk < rem)
            *(bf16x8*)&obuf[(size_t)tok_s[r_blk] * HD + colg0 + (lane & 7) * 8] = v;
    }
}

// ------------------------------------------------------------------ combine
__global__ __launch_bounds__(256) void combine_kernel(
    const ushort* __restrict__ obuf, float* __restrict__ out)
{
    int g = blockIdx.x * 256 + threadIdx.x;      // grid 4096 -> 1M threads
    int t = g >> 7, c8 = (g & 127) << 3;
    const ushort* p = obuf + (size_t)t * 2048 + c8;
    bf16x8 a = *(const bf16x8*)p;
    bf16x8 b = *(const bf16x8*)(p + 1024);
    float o[8];
#pragma unroll
    for (int i = 0; i < 8; i++)
        o[i] = bf2f((ushort)a[i]) + bf2f((ushort)b[i]);
    float* q = out + (size_t)t * HD + c8;
    *(float4*)q       = (float4){o[0], o[1], o[2], o[3]};
    *(float4*)(q + 4) = (float4){o[4], o[5], o[6], o[7]};
}

// ---------------------------------------------------------------- launcher
extern "C" void kernel_launch(void* const* d_in, const int* in_sizes, int n_in,
                              void* d_out, int out_size, void* d_ws, size_t ws_size,
                              hipStream_t stream)
{
    const float* x   = (const float*)d_in[0];
    const float* wrt = (const float*)d_in[1];
    const float* w1  = (const float*)d_in[2];
    const float* w2  = (const float*)d_in[3];
    float* out = (float*)d_out;

    // workspace carve (~80.3 MB); obuf aliases xb+w1b (dead after map_gemm)
    uint8_t* ws = (uint8_t*)d_ws;
    ushort* xb   = (ushort*)(ws);                    // 16 MB  [T][H] bf16
    ushort* w1b  = (ushort*)(ws + (16u << 20));      // 16 MB  [E][F][H] bf16
    ushort* obuf = (ushort*)(ws);                    // 32 MB  [2T][H] bf16 (alias)
    ushort* w2b  = (ushort*)(ws + (32u << 20));      // 16 MB  [E][H][F] bf16
    ushort* hbuf = (ushort*)(ws + (48u << 20));      // 32 MB  [2T][F] bf16
    uint8_t* p80 = ws + (80u << 20);
    int*   tok_list = (int*)(p80);                   // 64 KB
    float* w_list   = (float*)(p80 + (64u << 10));   // 64 KB
    int*   top_e    = (int*)(p80 + (128u << 10));    // 64 KB
    float* top_w    = (float*)(p80 + (192u << 10));  // 64 KB
    uint8_t* ctr    = p80 + (256u << 10);
    int*   counts   = (int*)(ctr);                   // 8 ints
    float* probsum  = (float*)(ctr + 64);            // 8 floats
    int*   offs     = (int*)(ctr + 128);             // 9 ints
    int*   cursor   = (int*)(ctr + 256);             // 8 * 16 ints (padded lines)
    float* loss_out = out + 8388608;

    hipMemsetAsync(ctr, 0, 1024, stream);

    router_kernel<<<512, 256, 0, stream>>>(x, wrt, xb, top_e, top_w, counts, probsum);
    wconv_kernel<<<2048, 256, 0, stream>>>(w1, w2, w1b, w2b);
    dispatch_kernel<<<32, 256, 0, stream>>>(counts, probsum, top_e, top_w,
                                            cursor, tok_list, w_list, offs, loss_out);
    // grid: rb(18) x nb(8) x e(8); e = low 3 bits -> XCD pin
    map_gemm<<<1152, 256, 0, stream>>>(xb, w1b, hbuf, tok_list, w_list, offs);
    reduce_gemm<<<1152, 256, 0, stream>>>(hbuf, w2b, obuf, tok_list, offs);
    combine_kernel<<<4096, 256, 0, stream>>>(obuf, out);
}

// Round 17
// 182.643 us; speedup vs baseline: 1.0480x; 1.0118x over previous
//
#include <hip/hip_runtime.h>
#include <hip/hip_bf16.h>
#include <stdint.h>

// dMoA forward: router(16 tok/block, LDS-wrt) -> w1/w2 transpose+convert
// (dbuf smem) -> dispatch(+prep) -> grouped map GEMM -> grouped reduce GEMM
// -> combine.  T=8192, H=F=1024, E=8, top-k=2.
// GEMM core (R6, best measured per-kernel): 256x256 tile, BK=64, 8 waves,
// dbuf LDS, 4-phase K-tile schedule (quadrant MFMA clusters, inline-asm
// ds_read_b128, early-issued stages, vmcnt(0)+barrier per K-tile),
// XOR-swizzled LDS, expert-pinned-to-XCD.  Periphery = R14 (best measured).

#define HD 1024
#define FD 1024
#define EN 8

typedef __attribute__((ext_vector_type(8))) short bf16x8;
typedef __attribute__((ext_vector_type(4))) float f32x4;

__device__ __forceinline__ void gload16(const void* g, void* l) {
    __builtin_amdgcn_global_load_lds(
        (const __attribute__((address_space(1))) unsigned int*)g,
        (__attribute__((address_space(3))) unsigned int*)l, 16, 0, 0);
}

// compiler-opaque LDS read: no implicit waitcnt edges get inserted.
__device__ __forceinline__ bf16x8 ds_read128(const short* p) {
    bf16x8 r;
    asm volatile("ds_read_b128 %0, %1"
                 : "=v"(r)
                 : "v"((const __attribute__((address_space(3))) short*)p));
    return r;
}

__device__ __forceinline__ ushort f2bf(float v) {
    __hip_bfloat16 h = __float2bfloat16(v);
    return *(ushort*)&h;
}
__device__ __forceinline__ float bf2f(ushort u) {
    unsigned int w = ((unsigned int)u) << 16;
    float f; __builtin_memcpy(&f, &w, 4); return f;
}

// ------------------------------------------------- router (+ x -> bf16 cast)
// 16 tokens/block (4/wave): wrt staged once per block (contiguous 128B/thread
// reads); compute reads lw[e][h0] as float4.
__global__ __launch_bounds__(256) void router_kernel(
    const float* __restrict__ x, const float* __restrict__ wrt,
    ushort* __restrict__ xb,
    int* __restrict__ top_e, float* __restrict__ top_w,
    int* __restrict__ counts, float* __restrict__ probsum)
{
    __shared__ float lw[EN][HD];     // 32 KB, transposed: lw[e][h]
    __shared__ int   cnt_s[EN];
    __shared__ float ps_s[EN];
    int tid = threadIdx.x;
    {   // stage wrt: thread tid covers h = 4*tid..4*tid+3 (contiguous 128B read)
        const float4* w4p = (const float4*)(wrt + (size_t)tid * 32);
#pragma unroll
        for (int q = 0; q < 4; q++) {
            float4 a = w4p[q * 2], b = w4p[q * 2 + 1];
            int h = tid * 4 + q;
            lw[0][h] = a.x; lw[1][h] = a.y; lw[2][h] = a.z; lw[3][h] = a.w;
            lw[4][h] = b.x; lw[5][h] = b.y; lw[6][h] = b.z; lw[7][h] = b.w;
        }
    }
    if (tid < EN) { cnt_s[tid] = 0; ps_s[tid] = 0.f; }
    __syncthreads();

    int wid = tid >> 6, lane = tid & 63;
#pragma unroll
    for (int j = 0; j < 4; j++) {
        int t = blockIdx.x * 16 + wid * 4 + j;   // 512 blocks * 16 = 8192
        const float4* xr4 = (const float4*)(x + (size_t)t * HD);
        ushort4* xbo = (ushort4*)(xb + (size_t)t * HD);
        float4 xv[4];
#pragma unroll
        for (int it = 0; it < 4; it++) xv[it] = xr4[it * 64 + lane];
#pragma unroll
        for (int it = 0; it < 4; it++) {
            ushort4 o; o.x = f2bf(xv[it].x); o.y = f2bf(xv[it].y);
            o.z = f2bf(xv[it].z); o.w = f2bf(xv[it].w);
            xbo[it * 64 + lane] = o;
        }
        float acc[EN];
#pragma unroll
        for (int e = 0; e < EN; e++) acc[e] = 0.f;
#pragma unroll
        for (int it = 0; it < 4; it++) {
            int h0 = it * 256 + lane * 4;
#pragma unroll
            for (int e = 0; e < EN; e++) {
                float4 w4 = *(const float4*)&lw[e][h0];
                acc[e] += xv[it].x * w4.x + xv[it].y * w4.y
                        + xv[it].z * w4.z + xv[it].w * w4.w;
            }
        }
#pragma unroll
        for (int off = 32; off >= 1; off >>= 1) {
#pragma unroll
            for (int e = 0; e < EN; e++) acc[e] += __shfl_xor(acc[e], off, 64);
        }
        if (lane == 0) {
            float m = acc[0];
#pragma unroll
            for (int e = 1; e < EN; e++) m = fmaxf(m, acc[e]);
            float p[EN], s = 0.f;
#pragma unroll
            for (int e = 0; e < EN; e++) { p[e] = expf(acc[e] - m); s += p[e]; }
            float inv = 1.f / s;
#pragma unroll
            for (int e = 0; e < EN; e++) p[e] *= inv;
            int e0 = 0;
#pragma unroll
            for (int e = 1; e < EN; e++) if (p[e] > p[e0]) e0 = e;  // strict >, first wins
            int e1 = (e0 == 0) ? 1 : 0;
#pragma unroll
            for (int e = 0; e < EN; e++) {
                if (e == e0) continue;
                if (p[e] > p[e1]) e1 = e;
            }
            top_e[t * 2] = e0;  top_e[t * 2 + 1] = e1;
            top_w[t * 2] = p[e0]; top_w[t * 2 + 1] = p[e1];
            atomicAdd(&cnt_s[e0], 1); atomicAdd(&cnt_s[e1], 1);
#pragma unroll
            for (int e = 0; e < EN; e++) atomicAdd(&ps_s[e], p[e]);
        }
    }
    __syncthreads();
    if (tid < EN) {
        atomicAdd(&counts[tid], cnt_s[tid]);
        atomicAdd(&probsum[tid], ps_s[tid]);
    }
}

// ---------------- w transpose + f32->bf16 convert (dbuf smem, 4 barriers)
__global__ __launch_bounds__(256) void wconv_kernel(
    const float* __restrict__ w1, const float* __restrict__ w2,
    ushort* __restrict__ w1b, ushort* __restrict__ w2b)
{
    __shared__ float smem[2][32 * 68];         // 17.4 KB double-buffered
    int bid = blockIdx.x;
    int tid = threadIdx.x;
    const float* in; ushort* outp;
    if (bid >= 1024) { in = w2; outp = w2b; bid -= 1024; }
    else             { in = w1; outp = w1b; }
    int e   = bid >> 7;
    int rm  = bid & 127;
    int kt  = rm >> 3;
    int ntg = rm & 7;
    const float* pin = in + ((size_t)e << 20) + (size_t)(kt * 64) * 1024 + ntg * 128;
    ushort* pout = outp + ((size_t)e << 20) + (size_t)(ntg * 128) * 1024 + kt * 64;

    int kk0 = tid >> 3, c4 = tid & 7;
    int kk1 = kk0 + 32;
    int n_r = tid >> 3, ks = (tid & 7) * 8;

    float4 v[8];
#pragma unroll
    for (int t = 0; t < 4; t++) {
        v[2 * t]     = *(const float4*)(pin + (size_t)kk0 * 1024 + t * 32 + c4 * 4);
        v[2 * t + 1] = *(const float4*)(pin + (size_t)kk1 * 1024 + t * 32 + c4 * 4);
    }
#pragma unroll
    for (int t = 0; t < 4; t++) {
        float* buf = smem[t & 1];
        float* d0 = &buf[(c4 * 4) * 68 + kk0];
        float* d1 = &buf[(c4 * 4) * 68 + kk1];
        d0[0] = v[2 * t].x; d0[68] = v[2 * t].y; d0[136] = v[2 * t].z; d0[204] = v[2 * t].w;
        d1[0] = v[2 * t + 1].x; d1[68] = v[2 * t + 1].y; d1[136] = v[2 * t + 1].z; d1[204] = v[2 * t + 1].w;
        __syncthreads();
        float4 f0 = *(const float4*)&buf[n_r * 68 + ks];
        float4 f1 = *(const float4*)&buf[n_r * 68 + ks + 4];
        ushort us[8];
        us[0] = f2bf(f0.x); us[1] = f2bf(f0.y); us[2] = f2bf(f0.z); us[3] = f2bf(f0.w);
        us[4] = f2bf(f1.x); us[5] = f2bf(f1.y); us[6] = f2bf(f1.z); us[7] = f2bf(f1.w);
        *(uint4*)(pout + (size_t)(t * 32 + n_r) * 1024 + ks) = *(uint4*)us;
    }
}

// ------------------------------------------- dispatch (+ inlined prep/loss)
__global__ __launch_bounds__(256) void dispatch_kernel(
    const int* __restrict__ counts, const float* __restrict__ probsum,
    const int* __restrict__ top_e, const float* __restrict__ top_w,
    int* __restrict__ cursor, int* __restrict__ tok_list,
    float* __restrict__ w_list, int* __restrict__ offs_g,
    float* __restrict__ loss_out)
{
    int offs[EN + 1]; offs[0] = 0;
#pragma unroll
    for (int e = 0; e < EN; e++) offs[e + 1] = offs[e] + counts[e];
    if (blockIdx.x == 0 && threadIdx.x == 0) {
        float loss = 0.f;
#pragma unroll
        for (int e = 0; e < EN; e++) {
            offs_g[e] = offs[e];
            loss += ((float)counts[e] / 16384.f) * (probsum[e] / 8192.f);
        }
        offs_g[EN] = offs[EN];
        *loss_out = 8.f * loss;
    }
    int t = blockIdx.x * 256 + threadIdx.x;   // grid 32*256 == 8192 exactly
    int lane = threadIdx.x & 63;
#pragma unroll
    for (int k = 0; k < 2; k++) {
        int e = top_e[t * 2 + k];
        int idx = 0;
#pragma unroll
        for (int ex = 0; ex < EN; ex++) {
            unsigned long long m = __ballot(e == ex);
            if (e == ex) {
                int cnt = __popcll(m);
                int leader = __ffsll(m) - 1;
                int pos = 0;
                if (lane == leader) pos = atomicAdd(&cursor[ex * 16], cnt);
                pos = __shfl(pos, leader, 64);
                int rank = __popcll(m & ((1ull << lane) - 1ull));
                idx = offs[ex] + pos + rank;
            }
        }
        tok_list[idx] = t * 2 + k;            // encode (token, k)
        w_list[idx] = top_w[t * 2 + k];
    }
}

// =================== grouped GEMM core (R6: 256x256, 4-phase) ==============
#define RDA(ml_, ks_) ds_read128(&lA[cur][wm * 128 + (ml_) * 16 + lo][(((ks_) * 4 + hi) ^ rx) << 3])
#define RDB(n_, ks_)  ds_read128(&lB[cur][wn * 64  + (n_) * 16 + lo][(((ks_) * 4 + hi) ^ rx) << 3])
#define MFMA_Q(mb_, nb_)                                                      \
    do {                                                                      \
        _Pragma("unroll") for (int ks = 0; ks < 2; ks++)                      \
        _Pragma("unroll") for (int ml = 0; ml < 4; ml++)                      \
        _Pragma("unroll") for (int nl = 0; nl < 2; nl++)                      \
            acc[(mb_) + ml][(nb_) + nl] =                                     \
                __builtin_amdgcn_mfma_f32_16x16x32_bf16(                      \
                    a[ml][ks], b[(nb_) + nl][ks], acc[(mb_) + ml][(nb_) + nl],\
                    0, 0, 0);                                                 \
    } while (0)
#define LGK0_FENCE()                                                          \
    do { asm volatile("s_waitcnt lgkmcnt(0)");                                \
         __builtin_amdgcn_sched_barrier(0); } while (0)
#define BOUNDARY()                                                            \
    do { asm volatile("s_waitcnt vmcnt(0)" ::: "memory");                     \
         __builtin_amdgcn_s_barrier();                                        \
         __builtin_amdgcn_sched_barrier(0); } while (0)

// --------------------------------------------------------- grouped map GEMM
__global__ __launch_bounds__(512, 2) void map_gemm(
    const ushort* __restrict__ xb, const ushort* __restrict__ w1b,
    ushort* __restrict__ hbuf,
    const int* __restrict__ tok_list, const float* __restrict__ w_list,
    const int* __restrict__ offs)
{
    __shared__ __align__(16) short lA[2][256][64];   // 64 KB
    __shared__ __align__(16) short lB[2][256][64];   // 64 KB
    __shared__ int   tok_s[256];
    __shared__ float wt_s[256];

    int g = blockIdx.x;
    int e = g & 7, q = g >> 3, nb = q & 3, rb = q >> 2;
    int base = offs[e], cnt = offs[e + 1] - base;
    int row0 = rb << 8;
    if (row0 >= cnt) return;
    int rem = cnt - row0;
    int tid = threadIdx.x;
    if (tid < 256) {
        int r = row0 + tid; if (r > cnt - 1) r = cnt - 1;   // clamp
        tok_s[tid] = tok_list[base + r];
        wt_s[tid]  = w_list[base + r];
    }
    __syncthreads();

    int lane = tid & 63, w = tid >> 6;
    int wm = w >> 2, wn = w & 3;
    int w32 = w * 32;
    int lr = lane >> 3;
    int kseg = ((lane & 7) ^ lr) << 3;        // pre-inverse-swizzled k-seg

    const ushort* pA[4]; const ushort* pB[4];
    const ushort* wbase = w1b + ((size_t)e << 20);
#pragma unroll
    for (int i = 0; i < 4; i++) {
        int rowT = w32 + i * 8 + lr;
        pA[i] = xb + (size_t)(tok_s[rowT] >> 1) * HD + kseg;
        pB[i] = wbase + (size_t)(nb * 256 + rowT) * HD + kseg;
    }

    f32x4 acc[8][4];
#pragma unroll
    for (int m = 0; m < 8; m++)
#pragma unroll
        for (int n = 0; n < 4; n++) acc[m][n] = (f32x4){0.f, 0.f, 0.f, 0.f};

    // prologue: stage K-tile 0 into buf0 (8 loads), drain, publish
#pragma unroll
    for (int i = 0; i < 4; i++) {
        gload16(pA[i], &lA[0][w32 + i * 8][0]);
        gload16(pB[i], &lB[0][w32 + i * 8][0]);
        pA[i] += 64; pB[i] += 64;
    }
    BOUNDARY();

    int lo = lane & 15, hi = lane >> 4, rx = lane & 7;
    bf16x8 a[4][2], b[4][2];

    for (int t = 0; t < 16; ++t) {
        int cur = t & 1, nxt = cur ^ 1;
        bool pf = (t < 15);
        // ---- phase 0: read A m0-3 + B n0-1; stage halves 0-1; MFMA (m0-3,n0-1)
#pragma unroll
        for (int ks = 0; ks < 2; ks++) {
            a[0][ks] = RDA(0, ks); a[1][ks] = RDA(1, ks);
            a[2][ks] = RDA(2, ks); a[3][ks] = RDA(3, ks);
            b[0][ks] = RDB(0, ks); b[1][ks] = RDB(1, ks);
        }
        if (pf) {
            gload16(pA[0], &lA[nxt][w32 + 0][0]);  pA[0] += 64;
            gload16(pB[0], &lB[nxt][w32 + 0][0]);  pB[0] += 64;
            gload16(pA[1], &lA[nxt][w32 + 8][0]);  pA[1] += 64;
            gload16(pB[1], &lB[nxt][w32 + 8][0]);  pB[1] += 64;
        }
        LGK0_FENCE();
        __builtin_amdgcn_s_setprio(1);
        MFMA_Q(0, 0);
        __builtin_amdgcn_s_setprio(0);
        __builtin_amdgcn_sched_barrier(0);
        // ---- phase 1: read B n2-3; stage halves 2-3; MFMA (m0-3,n2-3)
#pragma unroll
        for (int ks = 0; ks < 2; ks++) {
            b[2][ks] = RDB(2, ks); b[3][ks] = RDB(3, ks);
        }
        if (pf) {
            gload16(pA[2], &lA[nxt][w32 + 16][0]); pA[2] += 64;
            gload16(pB[2], &lB[nxt][w32 + 16][0]); pB[2] += 64;
            gload16(pA[3], &lA[nxt][w32 + 24][0]); pA[3] += 64;
            gload16(pB[3], &lB[nxt][w32 + 24][0]); pB[3] += 64;
        }
        LGK0_FENCE();
        __builtin_amdgcn_s_setprio(1);
        MFMA_Q(0, 2);
        __builtin_amdgcn_s_setprio(0);
        __builtin_amdgcn_sched_barrier(0);
        // ---- phase 2: read A m4-7 (overwrite a[]); MFMA (m4-7,n2-3)
#pragma unroll
        for (int ks = 0; ks < 2; ks++) {
            a[0][ks] = RDA(4, ks); a[1][ks] = RDA(5, ks);
            a[2][ks] = RDA(6, ks); a[3][ks] = RDA(7, ks);
        }
        LGK0_FENCE();
        __builtin_amdgcn_s_setprio(1);
        MFMA_Q(4, 2);
        __builtin_amdgcn_s_setprio(0);
        __builtin_amdgcn_sched_barrier(0);
        // ---- phase 3: no reads; MFMA (m4-7,n0-1)
        __builtin_amdgcn_s_setprio(1);
        MFMA_Q(4, 0);
        __builtin_amdgcn_s_setprio(0);
        __builtin_amdgcn_sched_barrier(0);
        // ---- K-tile boundary
        BOUNDARY();
    }

    // ---- epilogue: weight-fold, bf16, per-wave LDS transpose, 16B stores
    short* ep = (w < 4 ? (short*)lA : (short*)lB) + (w & 3) * 8192;  // 16KB/wave
#pragma unroll
    for (int m = 0; m < 8; m++)
#pragma unroll
        for (int r = 0; r < 4; r++) {
            int row_l = m * 16 + hi * 4 + r;
            int rswz = (row_l & 7) << 4;
            float wgt = wt_s[wm * 128 + row_l];
#pragma unroll
            for (int n = 0; n < 4; n++) {
                int colb = (n * 16 + lo) * 2;
                ep[(row_l * 128 + (colb ^ rswz)) >> 1] = f2bf(acc[m][n][r] * wgt);
            }
        }
    __syncthreads();
    size_t outbase = (size_t)(base + row0);
    int colg0 = (nb << 8) + wn * 64;
#pragma unroll
    for (int j = 0; j < 16; j++) {
        int row_l = j * 8 + (lane >> 3);
        int r_blk = wm * 128 + row_l;
        int sb = ((lane & 7) * 16) ^ ((row_l & 7) << 4);
        bf16x8 v = *(const bf16x8*)&ep[(row_l * 128 + sb) >> 1];
        if (r_blk < rem)
            *(bf16x8*)&hbuf[(outbase + r_blk) * FD + colg0 + (lane & 7) * 8] = v;
    }
}

// ------------------------------------------------------ grouped reduce GEMM
// obuf[v][:] = h[row][:] @ w2[e]  (v = tok_list row id = t*2+k), bf16 out.
__global__ __launch_bounds__(512, 2) void reduce_gemm(
    const ushort* __restrict__ hbuf, const ushort* __restrict__ w2b,
    ushort* __restrict__ obuf,
    const int* __restrict__ tok_list, const int* __restrict__ offs)
{
    __shared__ __align__(16) short lA[2][256][64];
    __shared__ __align__(16) short lB[2][256][64];
    __shared__ int tok_s[256];

    int g = blockIdx.x;
    int e = g & 7, q = g >> 3, nb = q & 3, rb = q >> 2;
    int base = offs[e], cnt = offs[e + 1] - base;
    int row0 = rb << 8;
    if (row0 >= cnt) return;
    int rem = cnt - row0;
    int tid = threadIdx.x;
    if (tid < 256) {
        int r = row0 + tid; if (r > cnt - 1) r = cnt - 1;
        tok_s[tid] = tok_list[base + r];
    }
    __syncthreads();

    int lane = tid & 63, w = tid >> 6;
    int wm = w >> 2, wn = w & 3;
    int w32 = w * 32;
    int lr = lane >> 3;
    int kseg = ((lane & 7) ^ lr) << 3;

    const ushort* pA[4]; const ushort* pB[4];
    const ushort* wbase = w2b + ((size_t)e << 20);
#pragma unroll
    for (int i = 0; i < 4; i++) {
        int rowT = w32 + i * 8 + lr;
        int ar = row0 + rowT; if (ar > cnt - 1) ar = cnt - 1;
        pA[i] = hbuf + (size_t)(base + ar) * FD + kseg;
        pB[i] = wbase + (size_t)(nb * 256 + rowT) * FD + kseg;
    }

    f32x4 acc[8][4];
#pragma unroll
    for (int m = 0; m < 8; m++)
#pragma unroll
        for (int n = 0; n < 4; n++) acc[m][n] = (f32x4){0.f, 0.f, 0.f, 0.f};

#pragma unroll
    for (int i = 0; i < 4; i++) {
        gload16(pA[i], &lA[0][w32 + i * 8][0]);
        gload16(pB[i], &lB[0][w32 + i * 8][0]);
        pA[i] += 64; pB[i] += 64;
    }
    BOUNDARY();

    int lo = lane & 15, hi = lane >> 4, rx = lane & 7;
    bf16x8 a[4][2], b[4][2];

    for (int t = 0; t < 16; ++t) {
        int cur = t & 1, nxt = cur ^ 1;
        bool pf = (t < 15);
        // ---- phase 0
#pragma unroll
        for (int ks = 0; ks < 2; ks++) {
            a[0][ks] = RDA(0, ks); a[1][ks] = RDA(1, ks);
            a[2][ks] = RDA(2, ks); a[3][ks] = RDA(3, ks);
            b[0][ks] = RDB(0, ks); b[1][ks] = RDB(1, ks);
        }
        if (pf) {
            gload16(pA[0], &lA[nxt][w32 + 0][0]);  pA[0] += 64;
            gload16(pB[0], &lB[nxt][w32 + 0][0]);  pB[0] += 64;
            gload16(pA[1], &lA[nxt][w32 + 8][0]);  pA[1] += 64;
            gload16(pB[1], &lB[nxt][w32 + 8][0]);  pB[1] += 64;
        }
        LGK0_FENCE();
        __builtin_amdgcn_s_setprio(1);
        MFMA_Q(0, 0);
        __builtin_amdgcn_s_setprio(0);
        __builtin_amdgcn_sched_barrier(0);
        // ---- phase 1
#pragma unroll
        for (int ks = 0; ks < 2; ks++) {
            b[2][ks] = RDB(2, ks); b[3][ks] = RDB(3, ks);
        }
        if (pf) {
            gload16(pA[2], &lA[nxt][w32 + 16][0]); pA[2] += 64;
            gload16(pB[2], &lB[nxt][w32 + 16][0]); pB[2] += 64;
            gload16(pA[3], &lA[nxt][w32 + 24][0]); pA[3] += 64;
            gload16(pB[3], &lB[nxt][w32 + 24][0]); pB[3] += 64;
        }
        LGK0_FENCE();
        __builtin_amdgcn_s_setprio(1);
        MFMA_Q(0, 2);
        __builtin_amdgcn_s_setprio(0);
        __builtin_amdgcn_sched_barrier(0);
        // ---- phase 2
#pragma unroll
        for (int ks = 0; ks < 2; ks++) {
            a[0][ks] = RDA(4, ks); a[1][ks] = RDA(5, ks);
            a[2][ks] = RDA(6, ks); a[3][ks] = RDA(7, ks);
        }
        LGK0_FENCE();
        __builtin_amdgcn_s_setprio(1);
        MFMA_Q(4, 2);
        __builtin_amdgcn_s_setprio(0);
        __builtin_amdgcn_sched_barrier(0);
        // ---- phase 3
        __builtin_amdgcn_s_setprio(1);
        MFMA_Q(4, 0);
        __builtin_amdgcn_s_setprio(0);
        __builtin_amdgcn_sched_barrier(0);
        // ---- K-tile boundary
        BOUNDARY();
    }

    // ---- epilogue: bf16, per-wave LDS transpose, scatter rows (128B segs)
    short* ep = (w < 4 ? (short*)lA : (short*)lB) + (w & 3) * 8192;
#pragma unroll
    for (int m = 0; m < 8; m++)
#pragma unroll
        for (int r = 0; r < 4; r++) {
            int row_l = m * 16 + hi * 4 + r;
            int rswz = (row_l & 7) << 4;
#pragma unroll
            for (int n = 0; n < 4; n++) {
                int colb = (n * 16 + lo) * 2;
                ep[(row_l * 128 + (colb ^ rswz)) >> 1] = f2bf(acc[m][n][r]);
            }
        }
    __syncthreads();
    int colg0 = (nb << 8) + wn * 64;
#pragma unroll
    for (int j = 0; j < 16; j++) {
        int row_l = j * 8 + (lane >> 3);
        int r_blk = wm * 128 + row_l;
        int sb = ((lane & 7) * 16) ^ ((row_l & 7) << 4);
        bf16x8 v = *(const bf16x8*)&ep[(row_l * 128 + sb) >> 1];
        if (r_blk < rem)
            *(bf16x8*)&obuf[(size_t)tok_s[r_blk] * HD + colg0 + (lane & 7) * 8] = v;
    }
}

// ------------------------------------------------------------------ combine
__global__ __launch_bounds__(256) void combine_kernel(
    const ushort* __restrict__ obuf, float* __restrict__ out)
{
    int g = blockIdx.x * 256 + threadIdx.x;      // grid 4096 -> 1M threads
    int t = g >> 7, c8 = (g & 127) << 3;
    const ushort* p = obuf + (size_t)t * 2048 + c8;
    bf16x8 a = *(const bf16x8*)p;
    bf16x8 b = *(const bf16x8*)(p + 1024);
    float o[8];
#pragma unroll
    for (int i = 0; i < 8; i++)
        o[i] = bf2f((ushort)a[i]) + bf2f((ushort)b[i]);
    float* q = out + (size_t)t * HD + c8;
    *(float4*)q       = (float4){o[0], o[1], o[2], o[3]};
    *(float4*)(q + 4) = (float4){o[4], o[5], o[6], o[7]};
}

// ---------------------------------------------------------------- launcher
extern "C" void kernel_launch(void* const* d_in, const int* in_sizes, int n_in,
                              void* d_out, int out_size, void* d_ws, size_t ws_size,
                              hipStream_t stream)
{
    const float* x   = (const float*)d_in[0];
    const float* wrt = (const float*)d_in[1];
    const float* w1  = (const float*)d_in[2];
    const float* w2  = (const float*)d_in[3];
    float* out = (float*)d_out;

    // workspace carve (~80.3 MB); obuf aliases xb+w1b (dead after map_gemm)
    uint8_t* ws = (uint8_t*)d_ws;
    ushort* xb   = (ushort*)(ws);                    // 16 MB  [T][H] bf16
    ushort* w1b  = (ushort*)(ws + (16u << 20));      // 16 MB  [E][F][H] bf16
    ushort* obuf = (ushort*)(ws);                    // 32 MB  [2T][H] bf16 (alias)
    ushort* w2b  = (ushort*)(ws + (32u << 20));      // 16 MB  [E][H][F] bf16
    ushort* hbuf = (ushort*)(ws + (48u << 20));      // 32 MB  [2T][F] bf16
    uint8_t* p80 = ws + (80u << 20);
    int*   tok_list = (int*)(p80);                   // 64 KB
    float* w_list   = (float*)(p80 + (64u << 10));   // 64 KB
    int*   top_e    = (int*)(p80 + (128u << 10));    // 64 KB
    float* top_w    = (float*)(p80 + (192u << 10));  // 64 KB
    uint8_t* ctr    = p80 + (256u << 10);
    int*   counts   = (int*)(ctr);                   // 8 ints
    float* probsum  = (float*)(ctr + 64);            // 8 floats
    int*   offs     = (int*)(ctr + 128);             // 9 ints
    int*   cursor   = (int*)(ctr + 256);             // 8 * 16 ints (padded lines)
    float* loss_out = out + 8388608;

    hipMemsetAsync(ctr, 0, 1024, stream);

    router_kernel<<<512, 256, 0, stream>>>(x, wrt, xb, top_e, top_w, counts, probsum);
    wconv_kernel<<<2048, 256, 0, stream>>>(w1, w2, w1b, w2b);
    dispatch_kernel<<<32, 256, 0, stream>>>(counts, probsum, top_e, top_w,
                                            cursor, tok_list, w_list, offs, loss_out);
    // grid 1024 = rb(32) x nb(4) x e(8); e = low 3 bits -> XCD pin
    map_gemm<<<1024, 512, 0, stream>>>(xb, w1b, hbuf, tok_list, w_list, offs);
    reduce_gemm<<<1024, 512, 0, stream>>>(hbuf, w2b, obuf, tok_list, offs);
    combine_kernel<<<4096, 256, 0, stream>>>(obuf, out);
}